// Round 1
// baseline (107.618 us; speedup 1.0000x reference)
//
#include <hip/hip_runtime.h>

#define BATCH 32
#define NROI  2000
#define NGT   100
#define NLBL  21
#define NPOS  64

// ---------------------------------------------------------------------------
// K1: per (b, roi) compute max IoU over the 100 gt boxes (strict-> argmax =
// first max, matching jnp.argmax). Store a composite ranking key:
//   key = (float_bits(max_iou) << 16) | (0xFFFF - roi)
// IoU >= 0 so float bits are monotonic; lower roi index wins ties (stable
// descending argsort semantics). All IoU arithmetic uses _rn intrinsics to
// forbid FMA contraction -> bit-match the numpy reference.
// ---------------------------------------------------------------------------
__global__ __launch_bounds__(256) void iou_max_kernel(
    const float4* __restrict__ roi, const float4* __restrict__ gt,
    unsigned long long* __restrict__ keys, int* __restrict__ maxidx) {
  __shared__ float4 sgt[NGT];
  const int b = blockIdx.y;
  const int r = blockIdx.x * 256 + threadIdx.x;
  if (threadIdx.x < NGT) sgt[threadIdx.x] = gt[b * NGT + threadIdx.x];
  __syncthreads();
  if (r >= NROI) return;
  // box layout [y1,x1,y2,x2]: .x=y1 .y=x1 .z=y2 .w=x2
  float4 rb = roi[b * NROI + r];
  float bb_area = __fmul_rn(__fsub_rn(rb.z, rb.x), __fsub_rn(rb.w, rb.y));
  float best = -1.0f;
  int bi = 0;
#pragma unroll 4
  for (int m = 0; m < NGT; ++m) {
    float4 g = sgt[m];
    float ga = __fmul_rn(__fsub_rn(g.z, g.x), __fsub_rn(g.w, g.y));
    float xt = fmaxf(rb.y, g.y);
    float yt = fmaxf(rb.x, g.x);
    float xb = fminf(rb.w, g.w);
    float yb = fminf(rb.z, g.z);
    float iw = fmaxf(__fsub_rn(xb, xt), 0.0f);
    float ih = fmaxf(__fsub_rn(yb, yt), 0.0f);
    float inter = __fmul_rn(iw, ih);
    float uni = __fsub_rn(__fadd_rn(bb_area, ga), inter);  // (bb+ga)-inter, left-to-right
    float iou = __fdiv_rn(inter, uni);
    if (iou > best) { best = iou; bi = m; }
  }
  unsigned int fb = __float_as_uint(best);  // best >= 0 always (union > 0)
  keys[b * NROI + r] =
      ((unsigned long long)fb << 16) | (unsigned long long)(0xFFFFu - (unsigned)r);
  maxidx[b * NROI + r] = bi;
}

// ---------------------------------------------------------------------------
// K2: one block per batch. Binary-search the 64th-largest key K64 (keys are
// distinct, so pos <=> key >= K64). Keys live in registers (8/thread); each
// search step is a block-wide count-greater reduction (<=46 steps over the
// 46-bit key space). Then compute deltas + label per positive roi.
// ---------------------------------------------------------------------------
__global__ __launch_bounds__(256) void select_delta_kernel(
    const unsigned long long* __restrict__ keys, const int* __restrict__ maxidx,
    const float4* __restrict__ roi, const float4* __restrict__ gt,
    const int* __restrict__ gtlab,
    float4* __restrict__ dlt, int* __restrict__ lab) {
  const int b = blockIdx.x;
  const int t = threadIdx.x;
  unsigned long long k[8];
#pragma unroll
  for (int j = 0; j < 8; ++j) {
    int i = t + j * 256;
    k[j] = (i < NROI) ? keys[b * NROI + i] : 0ull;  // dummy 0 never counts / never pos
  }
  __shared__ int scnt[4];
  unsigned long long lo = 0, hi = 0x3F800000FFFFull;  // max possible key (iou=1.0, r=0)
  while (lo < hi) {  // uniform across block: lo/hi identical on all threads
    unsigned long long mid = lo + ((hi - lo) >> 1);
    int c = 0;
#pragma unroll
    for (int j = 0; j < 8; ++j) c += (k[j] > mid) ? 1 : 0;
#pragma unroll
    for (int off = 32; off > 0; off >>= 1) c += __shfl_down(c, off, 64);
    if ((t & 63) == 0) scnt[t >> 6] = c;
    __syncthreads();
    int tot = scnt[0] + scnt[1] + scnt[2] + scnt[3];
    if (tot <= NPOS - 1) hi = mid; else lo = mid + 1;
    __syncthreads();
  }
  const unsigned long long k64 = lo;  // smallest T with count(>T) <= 63  == 64th largest
#pragma unroll
  for (int j = 0; j < 8; ++j) {
    int i = t + j * 256;
    if (i >= NROI) continue;
    int ridx = b * NROI + i;
    float4 d = make_float4(0.f, 0.f, 0.f, 0.f);
    int lb = 0;
    if (k[j] >= k64) {  // positive roi
      int mi = maxidx[ridx];
      float4 g = gt[b * NGT + mi];
      float4 rb = roi[ridx];
      float bw = rb.w - rb.y, bh = rb.z - rb.x;
      float bcx = rb.y + 0.5f * bw, bcy = rb.x + 0.5f * bh;
      float gw = g.w - g.y, gh = g.z - g.x;
      float gcx = g.y + 0.5f * gw, gcy = g.x + 0.5f * gh;
      if (bw == 0.f) bw = 1e-3f;
      if (bh == 0.f) bh = 1e-3f;
      float dx  = (gw == 0.f) ? 0.f : (gcx - bcx) / bw;
      float dy  = (gh == 0.f) ? 0.f : (gcy - bcy) / bh;
      float dwv = (gw == 0.f) ? 0.f : logf(gw / bw);
      float dhv = (gh == 0.f) ? 0.f : logf(gh / bh);
      d = make_float4(dy, dx, dhv, dwv);  // stack order [dy, dx, dh, dw]
      lb = gtlab[b * NGT + mi];
    }
    // negative roi: gt box = 0 -> gw=gh=0 -> all deltas 0; label 0 (one-hot class 0)
    dlt[ridx] = d;
    lab[ridx] = lb;
  }
}

// ---------------------------------------------------------------------------
// K3: coalesced float4 writer of both outputs.
//   out[0 .. 1343999]           : delta rows, one float4 per (b, roi, cls)
//   out[1344000 .. 1679999]     : labels, 4 consecutive fp32 per thread
// ---------------------------------------------------------------------------
__global__ __launch_bounds__(256) void write_out_kernel(
    const float4* __restrict__ dlt, const int* __restrict__ lab,
    float4* __restrict__ out) {
  const int ND4 = BATCH * NROI * NLBL;        // 1,344,000 delta float4 rows
  const int NL4 = (BATCH * NROI * NLBL) / 4;  //   336,000 label float4s
  int i = blockIdx.x * 256 + threadIdx.x;
  if (i < ND4) {
    int b = i / (NROI * NLBL);
    int rem = i - b * (NROI * NLBL);
    int r = rem / NLBL;
    int cls = rem - r * NLBL;
    int ridx = b * NROI + r;
    float4 v = make_float4(0.f, 0.f, 0.f, 0.f);
    if (cls == lab[ridx]) v = dlt[ridx];  // negatives: lab=0, dlt=0 -> zeros either way
    out[i] = v;
  } else if (i < ND4 + NL4) {
    int i2 = i - ND4;
    int e = i2 * 4;
    float v[4];
#pragma unroll
    for (int kk = 0; kk < 4; ++kk) {
      int ei = e + kk;
      int b = ei / (NROI * NLBL);
      int rem = ei - b * (NROI * NLBL);
      int r = rem / NLBL;
      int cls = rem - r * NLBL;
      v[kk] = (cls == lab[b * NROI + r]) ? 1.0f : 0.0f;
    }
    out[i] = make_float4(v[0], v[1], v[2], v[3]);
  }
}

extern "C" void kernel_launch(void* const* d_in, const int* in_sizes, int n_in,
                              void* d_out, int out_size, void* d_ws, size_t ws_size,
                              hipStream_t stream) {
  const float* roi = (const float*)d_in[0];  // (32,2000,4) fp32
  const float* gt  = (const float*)d_in[1];  // (32,100,4)  fp32
  const int* gtlab = (const int*)d_in[2];    // (32,100)    int32

  // workspace layout (bytes):
  //   [0,512000)           keys    u64[64000]
  //   [512000,768000)      maxidx  i32[64000]
  //   [768000,1792000)     dlt     float4[64000]   (16B aligned)
  //   [1792000,2048000)    lab     i32[64000]
  char* ws = (char*)d_ws;
  unsigned long long* keys = (unsigned long long*)ws;
  int*    maxidx = (int*)(ws + 512000);
  float4* dlt    = (float4*)(ws + 768000);
  int*    lab    = (int*)(ws + 1792000);

  iou_max_kernel<<<dim3(8, BATCH), 256, 0, stream>>>(
      (const float4*)roi, (const float4*)gt, keys, maxidx);
  select_delta_kernel<<<dim3(BATCH), 256, 0, stream>>>(
      keys, maxidx, (const float4*)roi, (const float4*)gt, gtlab, dlt, lab);
  const int total4 = BATCH * NROI * NLBL + (BATCH * NROI * NLBL) / 4;  // 1,680,000
  write_out_kernel<<<dim3((total4 + 255) / 256), 256, 0, stream>>>(
      dlt, lab, (float4*)d_out);
}

// Round 3
// 88.261 us; speedup vs baseline: 1.2193x; 1.2193x over previous
//
#include <hip/hip_runtime.h>

#define BATCH 32
#define NROI  2000
#define NGT   100
#define NLBL  21
#define NPOS  64

// native vector type for nontemporal stores (clang builtin rejects HIP float4)
typedef float nfloat4 __attribute__((ext_vector_type(4)));

__device__ __forceinline__ void nt_store(const float4& v, float4* p) {
  nfloat4 nv = {v.x, v.y, v.z, v.w};
  __builtin_nontemporal_store(nv, (nfloat4*)p);
}

// ---------------------------------------------------------------------------
// K1: per (b, roi) max/argmax IoU over 100 gt boxes (strict > = first-max,
// matching jnp.argmax). Composite rank key:
//   key = (float_bits(max_iou) << 16) | (0xFFFF - roi)
// iou >= 0 so float bits are order-monotonic; lower roi wins ties (stable
// descending argsort). _rn intrinsics forbid FMA contraction so the rounded
// quotients bit-match the numpy reference (selection flips are the only
// way to blow the 0.02 absmax threshold).
// ---------------------------------------------------------------------------
__global__ __launch_bounds__(256) void iou_max_kernel(
    const float4* __restrict__ roi, const float4* __restrict__ gt,
    unsigned long long* __restrict__ keys, int* __restrict__ maxidx) {
  __shared__ float4 sgt[NGT];
  __shared__ float sga[NGT];
  const int b = blockIdx.y;
  const int r = blockIdx.x * 256 + threadIdx.x;
  if (threadIdx.x < NGT) {
    float4 g = gt[b * NGT + threadIdx.x];
    sgt[threadIdx.x] = g;
    sga[threadIdx.x] = __fmul_rn(__fsub_rn(g.z, g.x), __fsub_rn(g.w, g.y));
  }
  __syncthreads();
  if (r >= NROI) return;
  // box layout [y1,x1,y2,x2]: .x=y1 .y=x1 .z=y2 .w=x2
  float4 rb = roi[b * NROI + r];
  float bb_area = __fmul_rn(__fsub_rn(rb.z, rb.x), __fsub_rn(rb.w, rb.y));
  float best = -1.0f;
  int bi = 0;
#pragma unroll 4
  for (int m = 0; m < NGT; ++m) {
    float4 g = sgt[m];
    float xt = fmaxf(rb.y, g.y);
    float yt = fmaxf(rb.x, g.x);
    float xb = fminf(rb.w, g.w);
    float yb = fminf(rb.z, g.z);
    float iw = fmaxf(__fsub_rn(xb, xt), 0.0f);
    float ih = fmaxf(__fsub_rn(yb, yt), 0.0f);
    float inter = __fmul_rn(iw, ih);
    float uni = __fsub_rn(__fadd_rn(bb_area, sga[m]), inter);  // left-to-right like np
    float iou = __fdiv_rn(inter, uni);
    if (iou > best) { best = iou; bi = m; }
  }
  unsigned int fb = __float_as_uint(best);
  keys[b * NROI + r] =
      ((unsigned long long)fb << 16) | (unsigned long long)(0xFFFFu - (unsigned)r);
  maxidx[b * NROI + r] = bi;
}

// ---------------------------------------------------------------------------
// K2: one block per batch. Radix-select the 64th-largest key (MSB-first,
// 8-bit digits, 6 passes over the 48-bit key space; keys < 2^46). Keys live
// in registers (8/thread). Each pass: LDS histogram (atomic) -> block-wide
// suffix scan (wave shuffles + 4 LDS partials) -> pick the bin holding the
// need-th largest. Keys are distinct so pos <=> key >= K64.
// Writes the "expanded gt box" (gt box for positives, zeros for negatives)
// and the expanded label per roi.
// ---------------------------------------------------------------------------
__global__ __launch_bounds__(256) void select_kernel(
    const unsigned long long* __restrict__ keys, const int* __restrict__ maxidx,
    const float4* __restrict__ gt, const int* __restrict__ gtlab,
    float4* __restrict__ egt, int* __restrict__ lab) {
  const int b = blockIdx.x;
  const int t = threadIdx.x;
  unsigned long long k[8];
#pragma unroll
  for (int j = 0; j < 8; ++j) {
    int i = t + j * 256;
    k[j] = (i < NROI) ? keys[b * NROI + i] : 0ull;  // dummy 0: never selected
  }
  __shared__ int hist[256];
  __shared__ int wtot[4];
  __shared__ int sbin, sneed;
  unsigned long long prefix = 0;
  int need = NPOS;  // 1-indexed rank of the boundary element
  const int lane = t & 63;
#pragma unroll
  for (int p = 0; p < 6; ++p) {
    const int shift = 40 - 8 * p;
    hist[t] = 0;
    __syncthreads();                               // B1: zeros visible
    const unsigned long long hmask = ~((1ull << (shift + 8)) - 1);
#pragma unroll
    for (int j = 0; j < 8; ++j) {
      if ((k[j] & hmask) == prefix)
        atomicAdd(&hist[(int)((k[j] >> shift) & 255)], 1);
    }
    __syncthreads();                               // B2: histogram complete
    int v = hist[t];
    int S = v;                                     // suffix sum within wave's 64 bins
#pragma unroll
    for (int off = 1; off < 64; off <<= 1) {
      int u = __shfl_down(S, off, 64);
      if (lane + off < 64) S += u;
    }
    if (lane == 0) wtot[t >> 6] = S;               // wave total (suffix from its bin 0)
    __syncthreads();                               // B3: wtot visible, hist reads done
    int w = t >> 6;
#pragma unroll
    for (int w2 = 1; w2 < 4; ++w2)
      if (w2 > w) S += wtot[w2];
    // unique crossing: S[t] >= need > S[t+1]  (S nonincreasing, S[0] >= need)
    if (S >= need && (S - v) < need) { sbin = t; sneed = need - (S - v); }
    __syncthreads();                               // B4: sbin/sneed visible
    prefix |= ((unsigned long long)sbin) << shift;
    need = sneed;
  }
  const unsigned long long k64 = prefix;  // exact key of the 64th largest
#pragma unroll
  for (int j = 0; j < 8; ++j) {
    int i = t + j * 256;
    if (i >= NROI) continue;
    int ridx = b * NROI + i;
    float4 g = make_float4(0.f, 0.f, 0.f, 0.f);
    int lb = 0;
    if (k[j] >= k64) {  // positive roi
      int mi = maxidx[ridx];
      g = gt[b * NGT + mi];
      lb = gtlab[b * NGT + mi];
    }
    egt[ridx] = g;   // expanded_gt_boxes semantics (zeros for negatives)
    lab[ridx] = lb;
  }
}

// ---------------------------------------------------------------------------
// K3: coalesced nontemporal float4 writer of both outputs; computes the
// delta in the single thread (cls == label) whose row is nonzero. Negative
// rois have egt = 0 -> gw = gh = 0 -> all deltas 0 (same guard as reference).
//   out[0 .. 1343999]       : delta rows, one float4 per (b, roi, cls)
//   out[1344000 .. 1679999] : labels, 4 consecutive fp32 per float4
// ---------------------------------------------------------------------------
__global__ __launch_bounds__(256) void write_out_kernel(
    const float4* __restrict__ roi, const float4* __restrict__ egt,
    const int* __restrict__ lab, float4* __restrict__ out) {
  const int ND4 = BATCH * NROI * NLBL;        // 1,344,000 delta float4 rows
  const int NL4 = (BATCH * NROI * NLBL) / 4;  //   336,000 label float4s
  int i = blockIdx.x * 256 + threadIdx.x;
  if (i < ND4) {
    int b = i / (NROI * NLBL);
    int rem = i - b * (NROI * NLBL);
    int r = rem / NLBL;
    int cls = rem - r * NLBL;
    int ridx = b * NROI + r;
    float4 v = make_float4(0.f, 0.f, 0.f, 0.f);
    if (cls == lab[ridx]) {
      float4 g = egt[ridx];
      float4 rb = roi[ridx];
      float bw = rb.w - rb.y, bh = rb.z - rb.x;
      float bcx = rb.y + 0.5f * bw, bcy = rb.x + 0.5f * bh;
      float gw = g.w - g.y, gh = g.z - g.x;
      float gcx = g.y + 0.5f * gw, gcy = g.x + 0.5f * gh;
      if (bw == 0.f) bw = 1e-3f;
      if (bh == 0.f) bh = 1e-3f;
      float dx  = (gw == 0.f) ? 0.f : (gcx - bcx) / bw;
      float dy  = (gh == 0.f) ? 0.f : (gcy - bcy) / bh;
      float dwv = (gw == 0.f) ? 0.f : logf(gw / bw);
      float dhv = (gh == 0.f) ? 0.f : logf(gh / bh);
      v = make_float4(dy, dx, dhv, dwv);  // [dy, dx, dh, dw]
    }
    nt_store(v, &out[i]);
  } else if (i < ND4 + NL4) {
    int i2 = i - ND4;
    int e = i2 * 4;
    float v[4];
#pragma unroll
    for (int kk = 0; kk < 4; ++kk) {
      int ei = e + kk;
      int b = ei / (NROI * NLBL);
      int rem = ei - b * (NROI * NLBL);
      int r = rem / NLBL;
      int cls = rem - r * NLBL;
      v[kk] = (cls == lab[b * NROI + r]) ? 1.0f : 0.0f;
    }
    float4 vv = make_float4(v[0], v[1], v[2], v[3]);
    nt_store(vv, &out[i]);
  }
}

extern "C" void kernel_launch(void* const* d_in, const int* in_sizes, int n_in,
                              void* d_out, int out_size, void* d_ws, size_t ws_size,
                              hipStream_t stream) {
  const float* roi = (const float*)d_in[0];  // (32,2000,4) fp32
  const float* gt  = (const float*)d_in[1];  // (32,100,4)  fp32
  const int* gtlab = (const int*)d_in[2];    // (32,100)    int32

  // workspace layout (bytes):
  //   [0,512000)           keys    u64[64000]
  //   [512000,768000)      maxidx  i32[64000]
  //   [768000,1792000)     egt     float4[64000]  (16B aligned: 768000/16=48000)
  //   [1792000,2048000)    lab     i32[64000]
  char* ws = (char*)d_ws;
  unsigned long long* keys = (unsigned long long*)ws;
  int*    maxidx = (int*)(ws + 512000);
  float4* egt    = (float4*)(ws + 768000);
  int*    lab    = (int*)(ws + 1792000);

  iou_max_kernel<<<dim3(8, BATCH), 256, 0, stream>>>(
      (const float4*)roi, (const float4*)gt, keys, maxidx);
  select_kernel<<<dim3(BATCH), 256, 0, stream>>>(
      keys, maxidx, (const float4*)gt, gtlab, egt, lab);
  const int total4 = BATCH * NROI * NLBL + (BATCH * NROI * NLBL) / 4;  // 1,680,000
  write_out_kernel<<<dim3((total4 + 255) / 256), 256, 0, stream>>>(
      (const float4*)roi, egt, lab, (float4*)d_out);
}